// Round 11
// baseline (166.085 us; speedup 1.0000x reference)
//
#include <hip/hip_runtime.h>

// PGA G(3,0,1) GeometricBilinear — bf16 MFMA R11: small-code fused kernel.
// P = 16384 positions. CIN=64, 2H=256, H=128, COUT=64, 16 blades.
//
// THEORY (R10 post-mortem): all fully-unrolled variants (R4/R9/R10) stall at
// 160-220us with MFMA<5%, VALU<11%, no spills, no HBM/LDS saturation — the
// unaccounted resource is L1I (32KB): ~40KB of unrolled code thrashes. R3's
// small loopy kernel issued at 71% VALUBusy. R11 keeps R10's verified math &
// schedule but shrinks code to ~15KB:
//  * weights repacked row-contiguous: w1c[o][1536], w2c[o2][3072] — every
//    load = one global_load_dwordx4 with compile-time imm offset off a
//    per-lane base (no per-site 64-bit address arith).
//  * LDS XOR-swizzles replaced by padded rows (X1 stride 272B, X2 544B,
//    epilogue 4112B): plain-add addressing, imm ds offsets, conflict-free.
//  * no explicit prefetch rings (compiler hoists from single-base loads).
// Verified mappings preserved: X1[row=e*16+pos][k=s*64+i]; MFMA 16x16x32
// A=weights(rows=channels) B=X1(cols=pos); D: pos=ln, ch=lh*4+r.
// X2[row=e2*16+pos][k2=s*128+cc]; out2 channel order [GP(64)|join(64)].

namespace {

constexpr int popc4(int v){int c=0;while(v){c+=v&1;v>>=1;}return c;}
constexpr float sgnf(int a,int b){int s=0;a>>=1;while(a){s+=popc4(a&b);a>>=1;}return (s&1)?-1.f:1.f;}

struct Tabs { float gp[16][16]; float jn[16][16]; };
constexpr Tabs mk(){
    Tabs t{};
    for(int a=0;a<16;a++)for(int b=0;b<16;b++){
        t.gp[a][b] = (a&b&1) ? 0.f : sgnf(a,b);
        if((a|b)==15){
            const int k = a&b;
            t.jn[a][b] = sgnf(a,15^a)*sgnf(b,15^b)*sgnf(15^a,15^b)*sgnf(k,15^k);
        } else t.jn[a][b] = 0.f;
    }
    return t;
}
constexpr Tabs TB = mk();
constexpr int GE[8] = {0,1,1,2,1,2,2,3};  // fallback kernel

// row-contiguous packed weights:
// w1c[o][1536]: for j=0..15 concat Wj[o][0..Kj), Kj = (j odd)?128:64
constexpr int BASE1(int j){ return (j>>1)*192 + ((j&1)?64:0); }
// w2c[o2][3072]: for j=0..15 concat W2j[o2][0..K2j), K2j = (j odd)?256:128
constexpr int BASE2(int j){ return (j>>1)*384 + ((j&1)?128:0); }
constexpr int W1C_ELEMS = 256*1536;   // 393216
constexpr int W2C_ELEMS = 64*3072;    // 196608

// LDS geometry (padded rows, no swizzle)
constexpr int X1_STRIDE = 272;        // 256B data + 16B pad
constexpr int X2_STRIDE = 544;        // 512B data + 32B pad
constexpr int EP_STRIDE = 4112;       // 4096B data + 16B pad
constexpr int X1_BYTES  = 128*X1_STRIDE;   // 34816
constexpr int X2_BYTES  = 128*X2_STRIDE;   // 69632 (>= 16*EP_STRIDE = 65792)

typedef short bf16x8 __attribute__((ext_vector_type(8)));
typedef float f32x4  __attribute__((ext_vector_type(4)));

__device__ inline unsigned short f2bf(float f){
    unsigned int u = __float_as_uint(f);
    u = u + 0x7fffu + ((u >> 16) & 1u);
    return (unsigned short)(u >> 16);
}
__device__ inline unsigned pack2(float a, float b){
    return (unsigned)f2bf(a) | ((unsigned)f2bf(b) << 16);
}

} // namespace

// ---------------- weight prep: pack into row-contiguous tables ---------------
__global__ void prep_w(const float* __restrict__ w1, const float* __restrict__ w2,
                       unsigned short* __restrict__ w1c, unsigned short* __restrict__ w2c)
{
    int idx = blockIdx.x * 256 + threadIdx.x;
    if (idx < W1C_ELEMS) {
        const int o = idx / 1536, r = idx - o*1536;
        const int p = r / 192, q = r - p*192;
        float v;
        if (q < 64) {                       // even j = 2p, k = q
            v = w1[(o*64 + q)*9 + popc4(2*p)];
        } else {                            // odd j = 2p+1, k = q-64
            const int j = 2*p + 1, k = q - 64, g = popc4(j);
            v = (k < 64) ? w1[(o*64 + k)*9 + g + 4]
                         : w1[(o*64 + (k - 64))*9 + g];
        }
        w1c[idx] = f2bf(v);
    } else {
        idx -= W1C_ELEMS;
        if (idx < W2C_ELEMS) {
            const int o = idx / 3072, r = idx - o*3072;
            const int p = r / 384, q = r - p*384;
            float v;
            if (q < 128) {                  // even j = 2p, k = q
                v = w2[(o*128 + q)*9 + popc4(2*p)];
            } else {                        // odd j = 2p+1, k = q-128
                const int j = 2*p + 1, k = q - 128, g = popc4(j);
                v = (k < 128) ? w2[(o*128 + k)*9 + g + 4]
                              : w2[(o*128 + (k - 128))*9 + g];
            }
            w2c[idx] = f2bf(v);
        }
    }
}

// ---------------- fused MFMA kernel: 1024 blocks x 512 thr (8 waves) ---------
__global__ __launch_bounds__(512, 2) void gb_mfma(
    const float* __restrict__ x, const float* __restrict__ ref,
    const float* __restrict__ b1, const float* __restrict__ b2,
    const unsigned short* __restrict__ w1c, const unsigned short* __restrict__ w2c,
    float* __restrict__ out)
{
    __shared__ __attribute__((aligned(16))) char X1[X1_BYTES];
    __shared__ __attribute__((aligned(16))) char X2[X2_BYTES];  // also epilogue f32
    __shared__ float lref[16];

    const int t   = threadIdx.x;
    const int bid = blockIdx.x;
    const int w   = t >> 6;        // wave 0..7
    const int l   = t & 63;
    const int ln  = l & 15;        // MFMA: position column
    const int lh  = l >> 4;        // MFMA: k-chunk / channel quad
    const int p0  = bid * 16;

    const int st  = w >> 2;        // 0 = geo, 1 = join
    const int grp = w & 3;
    const int f0  = (st == 0) ? grp : grp + 8;

    // per-lane bases (computed once)
    const unsigned short* pA = w1c + (f0*16 + ln)*1536;         // left rows
    const unsigned short* pB = w1c + ((f0+4)*16 + ln)*1536;     // right rows
    const unsigned short* pC = w2c + (grp*16 + ln)*3072 + 1536; // phase2 (centered)
    const int vX1 = ln*X1_STRIDE + lh*16;                       // X1 read base
    const int vX2 = ln*X2_STRIDE + lh*16;                       // X2 read base
    const int vX2w = ln*X2_STRIDE + w*32 + lh*8;                // X2 write base
    const int vEp  = ln*EP_STRIDE + grp*1024 + lh*256 + st*32;  // epilogue write base

    // ---- stage X1: x -> bf16 LDS [e*16+pos][s*128 + i*2], padded rows ----
    {
        const int spos = t >> 5;             // pos 0..15
        const int si0  = (t & 31) * 2;       // channel pair
        const float* gsrc = x + ((long)(p0 + spos))*1024 + si0*16;
        float4 v[8];
        #pragma unroll
        for (int a = 0; a < 8; ++a) v[a] = *(const float4*)(gsrc + a*4);
        char* base = X1 + spos*X1_STRIDE + si0*2;
        #pragma unroll
        for (int b = 0; b < 16; ++b) {
            const int e = b >> 1, s = b & 1;
            const float va = ((const float*)&v[b>>2])[b&3];
            const float vb = ((const float*)&v[4 + (b>>2)])[b&3];
            *(unsigned*)(base + e*16*X1_STRIDE + s*128) = pack2(va, vb);
        }
        if (t < 16) lref[t] = ref[((long)(p0 + t))*16 + 15];
    }
    __syncthreads();

    // ---- phase 1: left GEMM (16 static accumulators) ----
    f32x4 left[16];
    #pragma unroll
    for (int j = 0; j < 16; ++j) left[j] = (f32x4)0.f;

    #pragma unroll
    for (int j = 0; j < 16; ++j) {
        const int e = j >> 1, nkf = (j & 1) ? 4 : 2;
        #pragma unroll
        for (int kf = 0; kf < nkf; ++kf) {
            const bf16x8 a  = *(const bf16x8*)(pA + BASE1(j) + kf*32 + lh*8);
            const bf16x8 bx = *(const bf16x8*)(X1 + vX1 + e*16*X1_STRIDE + kf*64);
            left[j] = __builtin_amdgcn_mfma_f32_16x16x32_bf16(a, bx, left[j], 0, 0, 0);
        }
    }
    #pragma unroll
    for (int r = 0; r < 4; ++r) left[0][r] += b1[f0*16 + lh*4 + r];

    // ---- right blades streamed + product columns ----
    f32x4 prod[16];
    #pragma unroll
    for (int j = 0; j < 16; ++j) prod[j] = (f32x4)0.f;

    #pragma unroll
    for (int j = 0; j < 16; ++j) {
        const int e = j >> 1, nkf = (j & 1) ? 4 : 2;
        f32x4 right = (f32x4)0.f;
        #pragma unroll
        for (int kf = 0; kf < nkf; ++kf) {
            const bf16x8 a  = *(const bf16x8*)(pB + BASE1(j) + kf*32 + lh*8);
            const bf16x8 bx = *(const bf16x8*)(X1 + vX1 + e*16*X1_STRIDE + kf*64);
            right = __builtin_amdgcn_mfma_f32_16x16x32_bf16(a, bx, right, 0, 0, 0);
        }
        if (j == 0) {
            #pragma unroll
            for (int r = 0; r < 4; ++r) right[r] += b1[(f0+4)*16 + lh*4 + r];
        }
        if (st == 0) {
            #pragma unroll
            for (int A = 0; A < 16; ++A) {
                if (TB.gp[A][j] > 0.f)      prod[A ^ j] += left[A] * right;
                else if (TB.gp[A][j] < 0.f) prod[A ^ j] -= left[A] * right;
            }
        } else {
            #pragma unroll
            for (int A = 0; A < 16; ++A) {
                if (TB.jn[A][j] > 0.f)      prod[A & j] += left[A] * right;
                else if (TB.jn[A][j] < 0.f) prod[A & j] -= left[A] * right;
            }
        }
    }
    if (st == 1) {
        const float rv = lref[ln];
        #pragma unroll
        for (int j = 0; j < 16; ++j) prod[j] *= rv;
    }

    // ---- write prod -> X2 (4B pairs; base covers ln,w,lh) ----
    #pragma unroll
    for (int e2 = 0; e2 < 8; ++e2)
        #pragma unroll
        for (int s = 0; s < 2; ++s)
            #pragma unroll
            for (int rp = 0; rp < 4; rp += 2)
                *(unsigned*)(X2 + vX2w + e2*16*X2_STRIDE + s*256 + rp*2) =
                    pack2(prod[2*e2 + s][rp], prod[2*e2 + s][rp + 1]);
    __syncthreads();

    // ---- phase 2: wave = (st blade-half) x (grp o2-group) ----
    f32x4 acc2[8];
    #pragma unroll
    for (int jj = 0; jj < 8; ++jj) acc2[jj] = (f32x4)0.f;

    #pragma unroll
    for (int jj = 0; jj < 8; ++jj) {
        const int j2 = st*8 + jj;
        const int e2 = j2 >> 1, nkf = (j2 & 1) ? 8 : 4;
        #pragma unroll
        for (int kf = 0; kf < nkf; ++kf) {
            const bf16x8 a  = *(const bf16x8*)(pC + (BASE2(j2) - 1536) + kf*32 + lh*8);
            const bf16x8 bx = *(const bf16x8*)(X2 + vX2 + e2*16*X2_STRIDE + kf*64);
            acc2[jj] = __builtin_amdgcn_mfma_f32_16x16x32_bf16(a, bx, acc2[jj], 0, 0, 0);
        }
    }
    if (st == 0) {
        #pragma unroll
        for (int r = 0; r < 4; ++r) acc2[0][r] += b2[grp*16 + lh*4 + r];
    }
    __syncthreads();   // X2 reads done; region becomes epilogue buffer

    // ---- epilogue: acc2 -> LDS fp32 [pos][o2*16 + j], padded rows ----
    #pragma unroll
    for (int r = 0; r < 4; ++r) {
        *(float4*)(X2 + vEp + r*64)      = make_float4(acc2[0][r], acc2[1][r], acc2[2][r], acc2[3][r]);
        *(float4*)(X2 + vEp + r*64 + 16) = make_float4(acc2[4][r], acc2[5][r], acc2[6][r], acc2[7][r]);
    }
    __syncthreads();
    {
        const int pr = t >> 8;             // 0..1
        const int off = t & 255;
        const char* rbase = X2 + pr*EP_STRIDE + off*16;
        float* gbase = out + ((long)(p0 + pr))*1024 + off*4;
        #pragma unroll
        for (int it = 0; it < 8; ++it)
            *(float4*)(gbase + (long)it*2048) = *(const float4*)(rbase + it*2*EP_STRIDE);
    }
}

// ---------------- fp32 fallback (verified R3) --------------------------------
__global__ __launch_bounds__(256, 1) void gb_fused_f32(
    const float* __restrict__ x, const float* __restrict__ ref,
    const float* __restrict__ w1, const float* __restrict__ b1,
    const float* __restrict__ w2, const float* __restrict__ b2,
    float* __restrict__ out)
{
    __shared__ float lds[16384];
    __shared__ float lrefs[8];
    const int t = threadIdx.x;
    const int p0 = blockIdx.x * 8;
    {
        const float4* xg = reinterpret_cast<const float4*>(x) + (size_t)p0 * 256;
        float4* xl = reinterpret_cast<float4*>(lds);
        #pragma unroll
        for (int r = 0; r < 8; ++r) xl[r*256 + t] = xg[r*256 + t];
        if (t < 8) lrefs[t] = ref[(p0 + t)*16 + 15];
    }
    __syncthreads();
    const int c    = t & 127;
    const int half = t >> 7;
    const int ca   = (c < 64) ? c : (c + 64);
    const int cb   = ca + 64;
    float acc[4][2][16];
    #pragma unroll
    for (int q = 0; q < 4; ++q)
        #pragma unroll
        for (int s = 0; s < 2; ++s)
            #pragma unroll
            for (int j = 0; j < 16; ++j) acc[q][s][j] = 0.f;
    for (int i = 0; i < 64; ++i) {
        float wa[9], wb[9];
        #pragma unroll
        for (int r = 0; r < 9; ++r) { wa[r] = w1[(ca*64+i)*9 + r]; wb[r] = w1[(cb*64+i)*9 + r]; }
        #pragma unroll
        for (int q = 0; q < 4; ++q) {
            const float* xv = lds + (half*4 + q)*1024 + i*16;
            float xr[16];
            #pragma unroll
            for (int j4 = 0; j4 < 4; ++j4) {
                const float4 v = *reinterpret_cast<const float4*>(xv + 4*j4);
                xr[4*j4+0]=v.x; xr[4*j4+1]=v.y; xr[4*j4+2]=v.z; xr[4*j4+3]=v.w;
            }
            #pragma unroll
            for (int e = 0; e < 8; ++e) {
                const int ge = GE[e];
                const float xe = xr[2*e], xo = xr[2*e+1];
                acc[q][0][2*e]   += wa[ge]   * xe;
                acc[q][0][2*e+1] += wa[ge+1] * xo;
                acc[q][0][2*e+1] += wa[ge+5] * xe;
                acc[q][1][2*e]   += wb[ge]   * xe;
                acc[q][1][2*e+1] += wb[ge+1] * xo;
                acc[q][1][2*e+1] += wb[ge+5] * xe;
            }
        }
    }
    {
        const float ba = b1[ca], bb = b1[cb];
        #pragma unroll
        for (int q = 0; q < 4; ++q) { acc[q][0][0] += ba; acc[q][1][0] += bb; }
    }
    __syncthreads();
    #pragma unroll
    for (int q = 0; q < 4; ++q) {
        float prod[16];
        #pragma unroll
        for (int j = 0; j < 16; ++j) prod[j] = 0.f;
        if (c < 64) {
            #pragma unroll
            for (int A = 0; A < 16; ++A)
                #pragma unroll
                for (int B = 0; B < 16; ++B)
                    if (TB.gp[A][B] != 0.f)
                        prod[A ^ B] += TB.gp[A][B] * acc[q][0][A] * acc[q][1][B];
        } else {
            #pragma unroll
            for (int A = 0; A < 16; ++A)
                #pragma unroll
                for (int B = 0; B < 16; ++B)
                    if (TB.jn[A][B] != 0.f)
                        prod[A & B] += TB.jn[A][B] * acc[q][0][A] * acc[q][1][B];
            const float rp = lrefs[half*4 + q];
            #pragma unroll
            for (int j = 0; j < 16; ++j) prod[j] *= rp;
        }
        const int pos = half*4 + q;
        #pragma unroll
        for (int j4 = 0; j4 < 4; ++j4)
            *reinterpret_cast<float4*>(&lds[(pos*4 + j4)*512 + c*4]) =
                make_float4(prod[4*j4], prod[4*j4+1], prod[4*j4+2], prod[4*j4+3]);
    }
    __syncthreads();
    const int o    = t & 63;
    const int slot = t >> 6;
    float oacc[2][16];
    #pragma unroll
    for (int e2 = 0; e2 < 2; ++e2)
        #pragma unroll
        for (int j = 0; j < 16; ++j) oacc[e2][j] = 0.f;
    for (int i = 0; i < 128; ++i) {
        float wv[9];
        #pragma unroll
        for (int r = 0; r < 9; ++r) wv[r] = w2[(o*128+i)*9 + r];
        #pragma unroll
        for (int e2 = 0; e2 < 2; ++e2) {
            const int pos = slot*2 + e2;
            float xr[16];
            #pragma unroll
            for (int j4 = 0; j4 < 4; ++j4) {
                const float4 v = *reinterpret_cast<const float4*>(&lds[(pos*4 + j4)*512 + i*4]);
                xr[4*j4+0]=v.x; xr[4*j4+1]=v.y; xr[4*j4+2]=v.z; xr[4*j4+3]=v.w;
            }
            #pragma unroll
            for (int e = 0; e < 8; ++e) {
                const int ge = GE[e];
                oacc[e2][2*e]   += wv[ge]   * xr[2*e];
                oacc[e2][2*e+1] += wv[ge+1] * xr[2*e+1];
                oacc[e2][2*e+1] += wv[ge+5] * xr[2*e];
            }
        }
    }
    {
        const float bo = b2[o];
        #pragma unroll
        for (int e2 = 0; e2 < 2; ++e2) {
            oacc[e2][0] += bo;
            const int pos = p0 + slot*2 + e2;
            float* og = out + (size_t)pos*1024 + o*16;
            #pragma unroll
            for (int j4 = 0; j4 < 4; ++j4)
                *reinterpret_cast<float4*>(og + 4*j4) =
                    make_float4(oacc[e2][4*j4], oacc[e2][4*j4+1],
                                oacc[e2][4*j4+2], oacc[e2][4*j4+3]);
        }
    }
}

extern "C" void kernel_launch(void* const* d_in, const int* in_sizes, int n_in,
                              void* d_out, int out_size, void* d_ws, size_t ws_size,
                              hipStream_t stream)
{
    const float* x  = (const float*)d_in[0];
    const float* rf = (const float*)d_in[1];
    const float* w1 = (const float*)d_in[2];
    const float* b1 = (const float*)d_in[3];
    const float* w2 = (const float*)d_in[4];
    const float* b2 = (const float*)d_in[5];
    float* out = (float*)d_out;

    const size_t need = (size_t)(W1C_ELEMS + W2C_ELEMS) * sizeof(unsigned short);
    if (ws_size >= need) {
        unsigned short* w1c = (unsigned short*)d_ws;
        unsigned short* w2c = w1c + W1C_ELEMS;
        prep_w<<<(W1C_ELEMS + W2C_ELEMS)/256, 256, 0, stream>>>(w1, w2, w1c, w2c);
        gb_mfma<<<1024, 512, 0, stream>>>(x, rf, b1, b2, w1c, w2c, out);
    } else {
        gb_fused_f32<<<2048, 256, 0, stream>>>(x, rf, w1, b1, w2, b2, out);
    }
}